// Round 6
// baseline (158.536 us; speedup 1.0000x reference)
//
#include <hip/hip_runtime.h>

// DigitCaps dynamic routing, B=256 R=192 C=96 O=16 I=20. fp32 in/out.
// u_hat never materialized. 9 dispatches (R0 structure + R5 sigma-swz):
//   prep: W->WtT bf16 k-major; X->Xk + xT; bij=0 (bij C-MAJOR [c][r])
//   gemm1 (x3): 128m x 64n tile, split-K=15 (kChunk 256 = 4 iters of BK64,
//     each iter = 2 BK32 sub-tiles sharing ONE barrier), grid (2,24,15)=720;
//     A async global_load_lds(16B); B: it0 fully async, else reg-prefetch +
//     wave-local softmax scale at LDS-write; double LDS; partials bf16
//     P^T[z][n][b]; sigma-swizzled LDS (R5, neutral-but-free).
//   redsq (x3): grid (96,2); VECTORIZED uint4 P loads (was 60 scalar u16
//     loads/thread -> 15 uint4); LDS squash; -> vT/out. (R6)
//   gemm2_agree (x2): 128x64 tile, grid (30,24), fully async staging;
//     agreement epilogue reads WtT from LDS tile (reg-held through K-loop,
//     coalesced global read; was 16-lane 8B reads at stride 7680B). (R6)
// Lesson R1: __threadfence cross-block fusion = L2-writeback storm.
// Lesson R2/R3: 32x32 full-K tile = 2x L2/L3 traffic; split-K+TLP wins.
// Lesson R4: staging chunk order must keep 4-consecutive-chunks = one row.
// Lesson R5: LDS bank conflicts were TLP-hidden (sigma-swz neutral).

#define R_ 192
#define C_ 96
#define O_ 16
#define I_ 20
#define B_ 256
#define K1 3840   // R*I
#define N_ 1536   // C*O
#define ZSPLIT 15
#define KCH 256       // K1/ZSPLIT; 4 iters of BK=64 (2x BK32 sub-tiles)
#define STILE 393216  // N_*B_ elements per z-slice

typedef unsigned short u16;
typedef __attribute__((ext_vector_type(8))) short short8;
typedef __attribute__((ext_vector_type(4))) float floatx4;

__device__ inline float bf2f(u16 h) {
  union { unsigned int u; float f; } x; x.u = ((unsigned int)h) << 16; return x.f;
}
__device__ inline u16 f2bf(float f) {
  union { float f; unsigned int u; } x; x.f = f;
  unsigned int r = x.u + 0x7FFFu + ((x.u >> 16) & 1u);
  return (u16)(r >> 16);
}
__device__ inline unsigned int pack2(float a, float b) {
  return (unsigned int)f2bf(a) | ((unsigned int)f2bf(b) << 16);
}
// async 16B/lane global->LDS; lds base wave-uniform (lane scatters +16B)
__device__ inline void async16(const u16* g, u16* l) {
  __builtin_amdgcn_global_load_lds(
      (__attribute__((address_space(1))) void*)(unsigned long long)g,
      (__attribute__((address_space(3))) void*)(unsigned int)(unsigned long long)l,
      16, 0, 0);
}

// ---- fused prep: WtT gather (5760 blocks, 4 elems/thr); X cast+transpose
// (240); bij=0 c-major (18)
__global__ void k_prep(const float* __restrict__ W, const float* __restrict__ X,
                       u16* __restrict__ WtT, u16* __restrict__ Xk,
                       u16* __restrict__ xT, float* __restrict__ bij) {
  int bid = blockIdx.x;
  if (bid < 5760) {
    int t = (bid * 256 + threadIdx.x) << 2;    // 4-group stays in one n
    int n = t / K1, k = t - n * K1;
    int c = n >> 4, o = n & 15;
    const float* Wn = W + (size_t)(c * O_ + o) * I_;
    u16 h[4];
    #pragma unroll
    for (int e = 0; e < 4; ++e) {
      int ke = k + e, r = ke / I_, i = ke - r * I_;
      h[e] = f2bf(Wn[(size_t)r * (C_ * O_ * I_) + i]);
    }
    ushort4 o4; o4.x = h[0]; o4.y = h[1]; o4.z = h[2]; o4.w = h[3];
    *(ushort4*)&WtT[t] = o4;
  } else if (bid < 6000) {
    __shared__ u16 tile[64][72];
    int idx = bid - 5760;
    int kb = (idx % 60) << 6, bb = (idx / 60) << 6;
    int brow = threadIdx.x >> 4;          // 0..15
    int kq = (threadIdx.x & 15) << 2;     // 0..60 step 4
    #pragma unroll
    for (int p = 0; p < 4; ++p) {
      int bl = p * 16 + brow;
      float4 v = *(const float4*)(X + (size_t)(bb + bl) * K1 + kb + kq);
      ushort4 h;
      h.x = f2bf(v.x); h.y = f2bf(v.y); h.z = f2bf(v.z); h.w = f2bf(v.w);
      *(ushort4*)(Xk + (size_t)(bb + bl) * K1 + kb + kq) = h;
      tile[kq + 0][bl] = h.x;
      tile[kq + 1][bl] = h.y;
      tile[kq + 2][bl] = h.z;
      tile[kq + 3][bl] = h.w;
    }
    __syncthreads();
    int kr = threadIdx.x >> 3;            // 0..31
    int bq = (threadIdx.x & 7) << 3;      // 0..56 step 8
    #pragma unroll
    for (int q = 0; q < 2; ++q) {
      int kl = q * 32 + kr;
      *(uint4*)(xT + (size_t)(kb + kl) * B_ + bb + bq) = *(const uint4*)&tile[kl][bq];
    }
  } else {
    int t = ((bid - 6000) * 256 + threadIdx.x) << 2;  // bij: 18,432 floats
    if (t < R_ * C_) *(float4*)&bij[t] = (float4){0.f, 0.f, 0.f, 0.f};
  }
}

// scale 8 k-contiguous bf16 (global k = kg..kg+7) by softmax row(s)
__device__ inline uint4 scale_b8(uint4 raw, int kg, const float* smrow) {
  int r0 = kg / I_;
  int bnd = (r0 + 1) * I_ - kg;                // elements j<bnd use r0
  float s0 = smrow[r0];
  float s1 = smrow[(r0 + 1 < R_) ? r0 + 1 : R_ - 1];
  union { uint4 q; u16 h[8]; } u; u.q = raw;
  #pragma unroll
  for (int j = 0; j < 8; ++j)
    u.h[j] = f2bf(bf2f(u.h[j]) * ((j < bnd) ? s0 : s1));
  return u.q;
}

// LDS sigma-swizzle layout (per buffer, per matrix):
//   elem(sub, row, q, j) -> sub*(rows*32) + row*32 + ((q+(row>>1))&3)*8 + j
// Chunk id gc = sub*(rows*4) + row*4 + sigma; staged LINEARLY at gc*16B.
// Inverse (for staging source): row = cc>>2, sigma = cc&3,
//   q = (sigma - ((row>>1)&3)) & 3. Per 4 consecutive chunks: one row,
//   4 k-groups permuted inside one 64B global segment (full coalescing).

// ---- GEMM1: P^T[z][n][b] bf16 = (Xk[256,3840] x (c*WtT)[1536,3840]^T),
// k-chunk z (256 = 4 x BK64; each BK64 = 2 BK32 sub-tiles, ONE barrier).
// 128m x 64n tile, 4 waves of 64x32, grid (2,24,15)=720.
__global__ __launch_bounds__(256) void gemm1(
    const u16* __restrict__ A, const u16* __restrict__ Bt,
    const float* __restrict__ bij, u16* __restrict__ P, int doScale) {
  __shared__ u16 As[2][8192];   // 32 KB (sigma-swz)
  __shared__ u16 Bs[2][4096];   // 16 KB (sigma-swz)
  __shared__ float sm[4][192];
  int tid = threadIdx.x;
  int w = tid >> 6, lane = tid & 63;
  if (doScale) {  // wave-local softmax: wave w owns capsule (by<<2)+w
    int c = (blockIdx.y << 2) + w;
    float e0 = bij[c * R_ + lane];
    float e1 = bij[c * R_ + lane + 64];
    float e2 = bij[c * R_ + lane + 128];
    float mx = fmaxf(e0, fmaxf(e1, e2));
    #pragma unroll
    for (int off = 32; off > 0; off >>= 1) mx = fmaxf(mx, __shfl_xor(mx, off));
    e0 = expf(e0 - mx); e1 = expf(e1 - mx); e2 = expf(e2 - mx);
    float s = e0 + e1 + e2;
    #pragma unroll
    for (int off = 32; off > 0; off >>= 1) s += __shfl_xor(s, off);
    float inv = 1.0f / s;
    sm[w][lane] = e0 * inv;
    sm[w][lane + 64] = e1 * inv;
    sm[w][lane + 128] = e2 * inv;
  }

  long m0 = (long)blockIdx.x * 128, n0 = (long)blockIdx.y * 64;
  int k0 = blockIdx.z * KCH;
  const u16* Ab = A + m0 * K1 + k0;
  const u16* Bb = Bt + n0 * K1 + k0;
  // staging source permutation (wave-call covers 64 consecutive chunks):
  // lane l -> row_off = l>>2, k-group q_s = ((l&3) - ((l>>3)&3)) & 3.
  int q_s = ((lane & 3) - ((lane >> 3) & 3)) & 3;
  // A: call m (0..3): row = ((m&1)<<6) + (w<<4) + (l>>2);
  //    col = (m>>1)*32 + q_s*8; LDS base elem = (m<<11)+(w<<9).
  const u16* AgC[4]; int AlC[4];
  #pragma unroll
  for (int m = 0; m < 4; ++m) {
    AgC[m] = Ab + (long)(((m & 1) << 6) + (w << 4) + (lane >> 2)) * K1
             + ((m >> 1) << 5) + (q_s << 3);
    AlC[m] = (m << 11) + (w << 9);
  }
  // B async (it0): call m (0..1): row = (w<<4)+(l>>2); col = m*32 + q_s*8.
  const u16* BgC[2]; int BlC[2];
  #pragma unroll
  for (int m = 0; m < 2; ++m) {
    BgC[m] = Bb + (long)((w << 4) + (lane >> 2)) * K1 + (m << 5) + (q_s << 3);
    BlC[m] = (m << 11) + (w << 9);
  }
  // doScale reg-staging: thread tid -> chunk tid of sub0 (+ sub1 at +2048):
  // row = tid>>2, qD = ((tid&3) - ((tid>>3)&3)) & 3; write = linear 16B.
  int rowD = tid >> 2;
  int qD = ((tid & 3) - ((tid >> 3) & 3)) & 3;
  const u16* Bgs = Bb + (long)rowD * K1 + (qD << 3);
  const float* smrow = &sm[w][0];         // capsule of row rowD = rowD>>4 = w
  int wm = (w >> 1) << 6, wn = (w & 1) << 5;
  int quad = lane >> 4, lrow = lane & 15;
  int swz = ((quad + (lrow >> 1)) & 3) << 3;   // frag-read sigma slot
  floatx4 acc[4][2];
  #pragma unroll
  for (int a = 0; a < 4; ++a)
    #pragma unroll
    for (int b = 0; b < 2; ++b) acc[a][b] = (floatx4){0.f, 0.f, 0.f, 0.f};

  // kt=0 staging: both sub-tiles
  #pragma unroll
  for (int m = 0; m < 4; ++m) async16(AgC[m], &As[0][AlC[m]]);
  uint4 b0, b1;
  if (doScale) {
    b0 = *(const uint4*)Bgs;
    b1 = *(const uint4*)(Bgs + 32);
  } else {
    async16(BgC[0], &Bs[0][BlC[0]]);
    async16(BgC[1], &Bs[0][BlC[1]]);
  }
  __syncthreads();                   // asyncs drained; sm visible

  int p = 0;
  for (int kt = 0; kt < 4; ++kt) {
    if (doScale) {                   // thread's B k-cols: qD*8 (+32 sub1)
      int kg = k0 + (kt << 6) + (qD << 3);
      *(uint4*)&Bs[p][tid << 3] = scale_b8(b0, kg, smrow);
      *(uint4*)&Bs[p][2048 + (tid << 3)] = scale_b8(b1, kg + 32, smrow);
      __syncthreads();               // Bs[p] visible; As[p] asyncs complete
    } else if (kt > 0) {
      __syncthreads();               // buf p asyncs complete
    }
    if (kt + 1 < 4) {                // prefetch escapes the barrier drain
      int kk = (kt + 1) << 6;
      #pragma unroll
      for (int m = 0; m < 4; ++m) async16(AgC[m] + kk, &As[p ^ 1][AlC[m]]);
      if (doScale) {
        b0 = *(const uint4*)(Bgs + kk);
        b1 = *(const uint4*)(Bgs + kk + 32);
      } else {
        async16(BgC[0] + kk, &Bs[p ^ 1][BlC[0]]);
        async16(BgC[1] + kk, &Bs[p ^ 1][BlC[1]]);
      }
    }
    #pragma unroll
    for (int s = 0; s < 2; ++s) {
      short8 af[4], bfr[2];
      #pragma unroll
      for (int ms = 0; ms < 4; ++ms)
        af[ms] = *(const short8*)&As[p][(s << 12)
                                        + ((wm + ms * 16 + lrow) << 5) + swz];
      #pragma unroll
      for (int ns = 0; ns < 2; ++ns)
        bfr[ns] = *(const short8*)&Bs[p][(s << 11)
                                         + ((wn + ns * 16 + lrow) << 5) + swz];
      #pragma unroll
      for (int ms = 0; ms < 4; ++ms)
        #pragma unroll
        for (int ns = 0; ns < 2; ++ns)
          acc[ms][ns] = __builtin_amdgcn_mfma_f32_16x16x32_bf16(
              af[ms], bfr[ns], acc[ms][ns], 0, 0, 0);
    }
    p ^= 1;
  }
  // transposed bf16 store: P[z][n*256 + b]; lane holds 4 consecutive b
  size_t zb = (size_t)blockIdx.z * (size_t)STILE;
  #pragma unroll
  for (int ms = 0; ms < 4; ++ms)
    #pragma unroll
    for (int ns = 0; ns < 2; ++ns) {
      int b = (int)m0 + wm + ms * 16 + (quad << 2);
      int n = (int)n0 + wn + ns * 16 + lrow;
      uint2 pk;
      pk.x = pack2(acc[ms][ns][0], acc[ms][ns][1]);
      pk.y = pack2(acc[ms][ns][2], acc[ms][ns][3]);
      *(uint2*)&P[zb + (size_t)n * B_ + b] = pk;
    }
}

// ---- fused split-K reduce + squash, reading P^T[z][n][b] bf16.
// grid (96 c, 2 b-halves); block 256 = (n=t>>4) x (bgroup=t&15, 8 b each).
// 15 uint4 loads/thread (was 60 scalar u16). o-order in squash preserved
// -> bit-identical to R0/R5 redsq.
__global__ void k_redsq(const u16* __restrict__ P, float* __restrict__ out,
                        u16* __restrict__ vT, float preScale, int last) {
  __shared__ float sv[16][128];    // s values [o][b-local]
  __shared__ float f_l[128];       // squash factor per b-local
  int c = blockIdx.x, bh = blockIdx.y;
  int t = threadIdx.x;
  int n = t >> 4, bg = t & 15;
  const u16* base = P + (size_t)((c << 4) + n) * B_ + (bh << 7) + (bg << 3);
  float a[8];
  #pragma unroll
  for (int j = 0; j < 8; ++j) a[j] = 0.f;
  #pragma unroll
  for (int z = 0; z < ZSPLIT; ++z) {
    union { uint4 q; u16 h[8]; } u;
    u.q = *(const uint4*)(base + (size_t)z * STILE);
    #pragma unroll
    for (int j = 0; j < 8; ++j) a[j] += bf2f(u.h[j]);
  }
  #pragma unroll
  for (int j = 0; j < 8; ++j) sv[n][(bg << 3) + j] = a[j] * preScale;
  __syncthreads();
  if (t < 128) {                   // one b per thread; o-order 0..15
    float nsq = 0.f;
    #pragma unroll
    for (int o = 0; o < 16; ++o) { float v = sv[o][t]; nsq += v * v; }
    f_l[t] = nsq / ((1.0f + nsq) * sqrtf(nsq));
  }
  __syncthreads();
  if (last) {
    // thread t: b-local = t>>1, o-half = (t&1)*8; 2x float4 (64B/b-row)
    int bl = t >> 1, oh = (t & 1) << 3;
    float fv = f_l[bl];
    float* op = out + (size_t)((bh << 7) + bl) * N_ + (c << 4) + oh;
    float4 v0, v1;
    v0.x = sv[oh + 0][bl] * fv; v0.y = sv[oh + 1][bl] * fv;
    v0.z = sv[oh + 2][bl] * fv; v0.w = sv[oh + 3][bl] * fv;
    v1.x = sv[oh + 4][bl] * fv; v1.y = sv[oh + 5][bl] * fv;
    v1.z = sv[oh + 6][bl] * fv; v1.w = sv[oh + 7][bl] * fv;
    *(float4*)op = v0;
    *(float4*)(op + 4) = v1;
  } else {
    // vT[n][b] bf16: thread t keeps (n, bg); uint4 = 8 b packed
    int bs = bg << 3;
    uint4 o4; unsigned int* po = (unsigned int*)&o4;
    #pragma unroll
    for (int j = 0; j < 4; ++j) {
      float lo = sv[n][bs + 2 * j]     * f_l[bs + 2 * j];
      float hi = sv[n][bs + 2 * j + 1] * f_l[bs + 2 * j + 1];
      po[j] = pack2(lo, hi);
    }
    *(uint4*)&vT[(size_t)((c << 4) + n) * B_ + (bh << 7) + bs] = o4;
  }
}

// ---- GEMM2 + agreement fused, 128m x 64n tile, grid (30,24), K=256 =
// 4 x BK64 (2 BK32 sub-tiles per barrier), fully async staging; sigma-swz.
// R6: WtT epilogue tile (16KB) loaded coalesced into regs at entry (hidden
// under K-loop), spilled to LDS [ch][col] after loop; epilogue reads LDS.
__global__ __launch_bounds__(256) void gemm2_agree(
    const u16* __restrict__ A, const u16* __restrict__ Bt,
    const u16* __restrict__ WtT, float* __restrict__ bij) {
  const int K = 256;
  __shared__ u16 As[2][8192];
  __shared__ u16 Bs[2][4096];
  int tid = threadIdx.x;
  long m0 = (long)blockIdx.x * 128, n0 = (long)blockIdx.y * 64;
  const u16* Ab = A + m0 * K;
  const u16* Bb = Bt + n0 * K;
  int w = tid >> 6, lane = tid & 63;
  int wm = (w >> 1) << 6, wn = (w & 1) << 5;
  int quad = lane >> 4, lrow = lane & 15;
  int swz = ((quad + (lrow >> 1)) & 3) << 3;
  int q_s = ((lane & 3) - ((lane >> 3) & 3)) & 3;

  // Ws tile: WtT[n0+col][m0 + ch*8 .. +8], col=idx>>4, ch=idx&15;
  // coalesced 256B per 16 threads; reg-held until after the K-loop.
  uint4 wreg[4];
  #pragma unroll
  for (int j = 0; j < 4; ++j) {
    int idx = (j << 8) + tid;
    wreg[j] = *(const uint4*)&WtT[(size_t)(n0 + (idx >> 4)) * K1 + m0
                                  + ((idx & 15) << 3)];
  }

  const u16* AgC[4]; int AlC[4];
  #pragma unroll
  for (int m = 0; m < 4; ++m) {
    AgC[m] = Ab + (long)(((m & 1) << 6) + (w << 4) + (lane >> 2)) * K
             + ((m >> 1) << 5) + (q_s << 3);
    AlC[m] = (m << 11) + (w << 9);
  }
  const u16* BgC[2]; int BlC[2];
  #pragma unroll
  for (int m = 0; m < 2; ++m) {
    BgC[m] = Bb + (long)((w << 4) + (lane >> 2)) * K + (m << 5) + (q_s << 3);
    BlC[m] = (m << 11) + (w << 9);
  }
  floatx4 acc[4][2];
  #pragma unroll
  for (int a = 0; a < 4; ++a)
    #pragma unroll
    for (int b = 0; b < 2; ++b) acc[a][b] = (floatx4){0.f, 0.f, 0.f, 0.f};

  #pragma unroll
  for (int m = 0; m < 4; ++m) async16(AgC[m], &As[0][AlC[m]]);
  async16(BgC[0], &Bs[0][BlC[0]]);
  async16(BgC[1], &Bs[0][BlC[1]]);

  int p = 0;
  #pragma unroll
  for (int kt = 0; kt < 4; ++kt) {
    __syncthreads();                 // buf p asyncs complete
    if (kt + 1 < 4) {                // async prefetch escapes the drain
      int kk = (kt + 1) << 6;
      #pragma unroll
      for (int m = 0; m < 4; ++m) async16(AgC[m] + kk, &As[p ^ 1][AlC[m]]);
      async16(BgC[0] + kk, &Bs[p ^ 1][BlC[0]]);
      async16(BgC[1] + kk, &Bs[p ^ 1][BlC[1]]);
    }
    #pragma unroll
    for (int s = 0; s < 2; ++s) {
      short8 af[4], bfr[2];
      #pragma unroll
      for (int ms = 0; ms < 4; ++ms)
        af[ms] = *(const short8*)&As[p][(s << 12)
                                        + ((wm + ms * 16 + lrow) << 5) + swz];
      #pragma unroll
      for (int ns = 0; ns < 2; ++ns)
        bfr[ns] = *(const short8*)&Bs[p][(s << 11)
                                         + ((wn + ns * 16 + lrow) << 5) + swz];
      #pragma unroll
      for (int ms = 0; ms < 4; ++ms)
        #pragma unroll
        for (int ns = 0; ns < 2; ++ns)
          acc[ms][ns] = __builtin_amdgcn_mfma_f32_16x16x32_bf16(
              af[ms], bfr[ns], acc[ms][ns], 0, 0, 0);
    }
    p ^= 1;
  }

  // spill Ws regs -> LDS [ch=16][col=64] x 8 u16 (16KB, reuses As space)
  __syncthreads();                   // all frag reads done
  u16* Ws = (u16*)As;
  #pragma unroll
  for (int j = 0; j < 4; ++j) {
    int idx = (j << 8) + tid;
    *(uint4*)&Ws[(((idx & 15) << 6) + (idx >> 4)) << 3] = wreg[j];
  }
  __syncthreads();

  // epilogue: per fragment, cols = one capsule c; 16 rows span <=2 routes r.
  #pragma unroll
  for (int ms = 0; ms < 4; ++ms) {
    int rowbase = (int)m0 + wm + ms * 16;          // wave-uniform
    int r_lo = rowbase / I_;
    int r_hi = (rowbase + 15) / I_;
    int bnd = (r_lo + 1) * I_;
    int rlL = wm + ms * 16 + (quad << 2);          // local row 0..127
    int rowl = (int)m0 + rlL;
    int wbase = ((rlL >> 3) << 9) + ((rlL & 4) ? 4 : 0);  // ch*512 + half*4
    #pragma unroll
    for (int ns = 0; ns < 2; ++ns) {
      int colL = wn + ns * 16 + lrow;
      uint2 wv = *(const uint2*)&Ws[wbase + (colL << 3)];
      u16 h[4];
      h[0] = (u16)(wv.x & 0xffff); h[1] = (u16)(wv.x >> 16);
      h[2] = (u16)(wv.y & 0xffff); h[3] = (u16)(wv.y >> 16);
      float p0 = 0.f, p1 = 0.f;
      #pragma unroll
      for (int e = 0; e < 4; ++e) {
        float pr = acc[ms][ns][e] * bf2f(h[e]);
        if (rowl + e < bnd) p0 += pr; else p1 += pr;
      }
      #pragma unroll
      for (int off = 32; off > 0; off >>= 1) {
        p0 += __shfl_xor(p0, off);
        p1 += __shfl_xor(p1, off);
      }
      if (lane == 0) {
        int c = ((int)n0 + colL) >> 4;
        atomicAdd(&bij[c * R_ + r_lo], p0 * (1.0f / 256.0f));
        atomicAdd(&bij[c * R_ + r_hi], p1 * (1.0f / 256.0f));
      }
    }
  }
}

extern "C" void kernel_launch(void* const* d_in, const int* in_sizes, int n_in,
                              void* d_out, int out_size, void* d_ws, size_t ws_size,
                              hipStream_t stream) {
  const float* X = (const float*)d_in[0];   // fp32 [256,192,20]
  const float* W = (const float*)d_in[1];   // fp32 [192,96,16,20]
  float* out = (float*)d_out;               // fp32 [256,96,16]
  char* ws = (char*)d_ws;
  u16*  WtT = (u16*)(ws);                   // 11,796,480 B
  u16*  Xk  = (u16*)(ws + 11796480);        //  1,966,080 B
  u16*  xT  = (u16*)(ws + 13762560);        //  1,966,080 B
  u16*  vT  = (u16*)(ws + 15728640);        //    786,432 B
  u16*  Pb  = (u16*)(ws + 16515072);        // 15 z x 786,432 B = 11,796,480 B
  float* bij = (float*)(ws + 28311552);     //     73,728 B (c-major [c][r])

  k_prep<<<6018, 256, 0, stream>>>(W, X, WtT, Xk, xT, bij);

  for (int it = 0; it < 3; ++it) {
    // s partials: M=256,N=1536,K=3840, grid (2,24,15)=720, 4 BK64 iters.
    // iter 0: no scale in gemm1; uniform softmax 1/192 applied in redsq.
    gemm1<<<dim3(2, 24, ZSPLIT), 256, 0, stream>>>(Xk, WtT, bij, Pb, it > 0);
    k_redsq<<<dim3(96, 2), 256, 0, stream>>>(
        Pb, out, vT, it == 0 ? (1.0f / 192.0f) : 1.0f, it == 2);
    if (it < 2)
      gemm2_agree<<<dim3(30, 24), 256, 0, stream>>>(xT, vT, WtT, bij);
  }
}